// Round 5
// baseline (118.282 us; speedup 1.0000x reference)
//
#include <hip/hip_runtime.h>
#include <hip/hip_bf16.h>

// TripletLoss: fused E·E^T + masked row min/max reduction. B=8192, D=256.
// dist = sqrt(2-2*sim) monotone decreasing in sim =>
//   dist_ap = dist(min sim over positives), dist_an = dist(max sim over negatives).
//
// R5: SYMMETRY. C is symmetric, min/max folds are idempotent => compute only
// upper-triangular 256x256 panel pairs (528 blocks, 8 nn each vs R4's 512x16)
// and fold each element into BOTH its row anchor (registers + global atomics)
// and its col anchor (LDS colmin/colmax + one global atomic per col per block).
// Diagonal blocks double-fold symmetric duplicates -- harmless for min/max.
// Values are bitwise identical to R4's (same MFMA, same k order).

#define BDIM 8192
#define DDIM 256

typedef short bf16x8 __attribute__((ext_vector_type(8)));
typedef float f32x4  __attribute__((ext_vector_type(4)));
typedef unsigned short u16;

static __device__ __forceinline__ bf16x8 ld_frag(const u16* p) {
    return *reinterpret_cast<const bf16x8*>(p);
}

static __device__ __forceinline__ u16 f2bf(float f) {
    union { float f; unsigned int u; } x; x.f = f;
    unsigned int u = x.u;
    unsigned int r = u + 0x7fffu + ((u >> 16) & 1u);  // RNE
    return (u16)(r >> 16);
}

static __device__ __forceinline__ void gload_lds16(const u16* g, u16* l) {
    __builtin_amdgcn_global_load_lds(
        (const __attribute__((address_space(1))) unsigned int*)g,
        (__attribute__((address_space(3))) unsigned int*)l, 16, 0, 0);
}

// ---- kernel 1: fp32 -> bf16 convert + init reduction arrays ----
__global__ __launch_bounds__(256) void cvt_init_kernel(const float* __restrict__ in,
                                                       u16* __restrict__ out,
                                                       int* __restrict__ minpos,
                                                       int* __restrict__ maxneg) {
    int i = blockIdx.x * 256 + threadIdx.x;          // 524288 threads, 4 elems each
    const float4 v = reinterpret_cast<const float4*>(in)[i];
    ushort4 o;
    o.x = f2bf(v.x); o.y = f2bf(v.y); o.z = f2bf(v.z); o.w = f2bf(v.w);
    reinterpret_cast<ushort4*>(out)[i] = o;
    if (i < BDIM) {
        minpos[i] = 0x7f800000;                      // +inf  (min over positives of sim+2)
        maxneg[i] = 0;                               // 0.0f  (max over negatives of sim+2)
    }
}

// ---- kernel 2: fused GEMM + dual masked min/max (upper-tri panels) ----
// block = 256 thr = 4 waves; panel pair (i,j), j>=i, decoded from blockIdx.x.
// Wave w owns rows [i*256 + w*64, +64) (ms=4, a[4][8] register-resident).
// Block sweeps cols [j*256, +256), 32 at a time (nt=2); B-tile 32x256 = 16KB,
// double-buffered via global_load_lds w16; source-address XOR swizzle c^(r&7).
__global__ __launch_bounds__(256, 2) void triplet_main(const u16* __restrict__ Ebf,
                                                       const int* __restrict__ labels,
                                                       int* __restrict__ minpos,
                                                       int* __restrict__ maxneg) {
    __shared__ __align__(16) u16 smem[2][32 * DDIM];  // 2 x 16 KB
    __shared__ int colmin[256], colmax[256];
    __shared__ int labc[256];

    const int tid  = threadIdx.x;
    const int w    = tid >> 6;
    const int l    = tid & 63;
    const int quad = l >> 4;
    const int r16  = l & 15;

    // decode upper-triangular panel pair (i,j), 32 panels of 256
    int idx = blockIdx.x, pi = 0, base = 0;
    while (idx >= base + (32 - pi)) { base += (32 - pi); ++pi; }
    const int pj = pi + (idx - base);

    const int mblk  = pi * 256 + w * 64;             // wave's first row
    const int jbase = pj * 256;

    // per-block init of col state + col labels
    colmin[tid] = 0x7f800000;
    colmax[tid] = 0;
    labc[tid]   = labels[jbase + tid];

    // Preload A fragments: a[ms][k] covers rows [mblk+ms*16,+16), k-chunk [k*32,+32)
    bf16x8 a[4][8];
#pragma unroll
    for (int ms = 0; ms < 4; ++ms) {
        const u16* ap = Ebf + (size_t)(mblk + ms * 16 + r16) * DDIM + quad * 8;
#pragma unroll
        for (int k = 0; k < 8; ++k) a[ms][k] = ld_frag(ap + k * 32);
    }

    int lab_row[4][4];
#pragma unroll
    for (int ms = 0; ms < 4; ++ms)
#pragma unroll
        for (int r = 0; r < 4; ++r)
            lab_row[ms][r] = labels[mblk + ms * 16 + quad * 4 + r];

    float minp[4][4], maxn[4][4];
#pragma unroll
    for (int ms = 0; ms < 4; ++ms)
#pragma unroll
        for (int r = 0; r < 4; ++r) { minp[ms][r] = __builtin_inff(); maxn[ms][r] = -__builtin_inff(); }

    // swizzled-read lane constants
    const int qs = quad ^ (r16 & 3);
    const int s4 = (r16 >> 2) & 1;

    // stage first tile into buf 0
#pragma unroll
    for (int it = 0; it < 4; ++it) {
        const int q = it * 256 + tid;
        const int r = q >> 5;
        const int c = (q & 31) ^ (r & 7);
        gload_lds16(Ebf + ((size_t)(jbase + r) << 8) + c * 8,
                    &smem[0][0] + it * 2048 + w * 512);
    }

    const f32x4 zero4 = (f32x4){0.f, 0.f, 0.f, 0.f};

    for (int nn = 0; nn < 8; ++nn) {
        const int cur = nn & 1;
        const int n0  = jbase + nn * 32;

        __syncthreads();   // staging of smem[cur] (and init writes) complete

        if (nn + 1 < 8) {
            const int n1 = n0 + 32;
#pragma unroll
            for (int it = 0; it < 4; ++it) {
                const int q = it * 256 + tid;
                const int r = q >> 5;
                const int c = (q & 31) ^ (r & 7);
                gload_lds16(Ebf + ((size_t)(n1 + r) << 8) + c * 8,
                            &smem[cur ^ 1][0] + it * 2048 + w * 512);
            }
        }

        f32x4 acc[4][2];
        const u16* bb = &smem[cur][0];
        const u16* bnt[2];
#pragma unroll
        for (int nt = 0; nt < 2; ++nt)
            bnt[nt] = bb + (nt * 16 + r16) * DDIM + qs * 8;

        // k=0 peeled: C-operand is the shared zero vector (no acc re-zeroing)
        {
            const int koff = ((0 ^ s4) << 5);
            bf16x8 b[2];
#pragma unroll
            for (int nt = 0; nt < 2; ++nt) b[nt] = ld_frag(bnt[nt] + koff);
#pragma unroll
            for (int ms = 0; ms < 4; ++ms)
#pragma unroll
                for (int nt = 0; nt < 2; ++nt)
                    acc[ms][nt] = __builtin_amdgcn_mfma_f32_16x16x32_bf16(
                        a[ms][0], b[nt], zero4, 0, 0, 0);
        }
#pragma unroll
        for (int k = 1; k < 8; ++k) {
            const int koff = ((k ^ s4) << 5);
            bf16x8 b[2];
#pragma unroll
            for (int nt = 0; nt < 2; ++nt) b[nt] = ld_frag(bnt[nt] + koff);
#pragma unroll
            for (int ms = 0; ms < 4; ++ms)
#pragma unroll
                for (int nt = 0; nt < 2; ++nt)
                    acc[ms][nt] = __builtin_amdgcn_mfma_f32_16x16x32_bf16(
                        a[ms][k], b[nt], acc[ms][nt], 0, 0, 0);
        }

        // dual masked fold (row anchors in registers, col anchors via LDS)
        const bool diagTile = (n0 < mblk + 64) && (mblk < n0 + 32);
#pragma unroll
        for (int nt = 0; nt < 2; ++nt) {
            const int ci    = nn * 32 + nt * 16 + r16;   // block-local col
            const int lab_c = labc[ci - nn * 32 + nn * 32];  // = labc[ci]
            float cmin =  __builtin_inff();
            float cmax = -__builtin_inff();
            if (__builtin_expect(diagTile, 0)) {
                const int colg = n0 + nt * 16 + r16;
#pragma unroll
                for (int ms = 0; ms < 4; ++ms)
#pragma unroll
                    for (int r = 0; r < 4; ++r) {
                        const int rowg = mblk + ms * 16 + quad * 4 + r;
                        const float s = acc[ms][nt][r];
                        const bool same = (lab_c == lab_row[ms][r]);
                        const bool pos  = same && (colg != rowg);
                        const float v = pos  ?  s : __builtin_inff();
                        const float x = same ? -__builtin_inff() : s;
                        minp[ms][r] = fminf(minp[ms][r], v);
                        maxn[ms][r] = fmaxf(maxn[ms][r], x);
                        cmin = fminf(cmin, v);
                        cmax = fmaxf(cmax, x);
                    }
            } else {
#pragma unroll
                for (int ms = 0; ms < 4; ++ms)
#pragma unroll
                    for (int r = 0; r < 4; ++r) {
                        const float s = acc[ms][nt][r];
                        const bool same = (lab_c == lab_row[ms][r]);
                        const float v = same ?  s : __builtin_inff();
                        const float x = same ? -__builtin_inff() : s;
                        minp[ms][r] = fminf(minp[ms][r], v);
                        maxn[ms][r] = fmaxf(maxn[ms][r], x);
                        cmin = fminf(cmin, v);
                        cmax = fmaxf(cmax, x);
                    }
            }
            // reduce col candidates across the 4 quads (same col, different rows)
            cmin = fminf(cmin, __shfl_xor(cmin, 16, 64));
            cmin = fminf(cmin, __shfl_xor(cmin, 32, 64));
            cmax = fmaxf(cmax, __shfl_xor(cmax, 16, 64));
            cmax = fmaxf(cmax, __shfl_xor(cmax, 32, 64));
            if (quad == 0) {
                atomicMin(&colmin[ci], __float_as_int(cmin + 2.0f));
                atomicMax(&colmax[ci], __float_as_int(cmax + 2.0f));
            }
        }
    }

    // row anchors: reduce across the 16 lanes sharing a quad, then global atomics
#pragma unroll
    for (int mask = 1; mask <= 8; mask <<= 1) {
#pragma unroll
        for (int ms = 0; ms < 4; ++ms)
#pragma unroll
            for (int r = 0; r < 4; ++r) {
                minp[ms][r] = fminf(minp[ms][r], __shfl_xor(minp[ms][r], mask, 64));
                maxn[ms][r] = fmaxf(maxn[ms][r], __shfl_xor(maxn[ms][r], mask, 64));
            }
    }
    if (r16 == 0) {
#pragma unroll
        for (int ms = 0; ms < 4; ++ms)
#pragma unroll
            for (int r = 0; r < 4; ++r) {
                const int rowg = mblk + ms * 16 + quad * 4 + r;
                atomicMin(minpos + rowg, __float_as_int(minp[ms][r] + 2.0f));
                atomicMax(maxneg + rowg, __float_as_int(maxn[ms][r] + 2.0f));
            }
    }

    // col anchors: one global atomic pair per column
    __syncthreads();
    atomicMin(minpos + jbase + tid, colmin[tid]);
    atomicMax(maxneg + jbase + tid, colmax[tid]);
}

// ---- kernel 3: finalize (single block, 1024 threads) ----
__global__ __launch_bounds__(1024) void finalize_kernel(const int* __restrict__ minpos,
                                                        const int* __restrict__ maxneg,
                                                        float* __restrict__ out) {
    __shared__ float ssum[16], scnt[16];
    float sum = 0.f, cnt = 0.f;
#pragma unroll
    for (int it = 0; it < 8; ++it) {
        const int i = it * 1024 + threadIdx.x;
        const float mp = __int_as_float(minpos[i]);  // min(sim)+2 over positives; +inf if none
        const float mn = __int_as_float(maxneg[i]);  // max(sim)+2 over negatives; 0 if none
        if (mp < 1e30f && mn > 0.5f) {
            // dist = sqrt(2 - 2*sim), sim = stored - 2  =>  6 - 2*stored
            const float dap = sqrtf(fmaxf(6.0f - 2.0f * mp, 0.0f) + 1e-12f);
            const float dan = sqrtf(fmaxf(6.0f - 2.0f * mn, 0.0f) + 1e-12f);
            sum += fmaxf(dap - dan + 0.3f, 0.0f);
            cnt += 1.0f;
        }
    }
#pragma unroll
    for (int off = 32; off > 0; off >>= 1) {
        sum += __shfl_down(sum, off, 64);
        cnt += __shfl_down(cnt, off, 64);
    }
    const int wid = threadIdx.x >> 6;
    if ((threadIdx.x & 63) == 0) { ssum[wid] = sum; scnt[wid] = cnt; }
    __syncthreads();
    if (threadIdx.x == 0) {
        float S = 0.f, C = 0.f;
#pragma unroll
        for (int i = 0; i < 16; ++i) { S += ssum[i]; C += scnt[i]; }
        out[0] = (C > 0.f) ? (S / C) : 0.f;
    }
}

extern "C" void kernel_launch(void* const* d_in, const int* in_sizes, int n_in,
                              void* d_out, int out_size, void* d_ws, size_t ws_size,
                              hipStream_t stream) {
    const float* emb    = (const float*)d_in[0];
    const int*   labels = (const int*)d_in[1];
    float*       out    = (float*)d_out;

    u16* Ebf    = (u16*)d_ws;                                  // 4 MB
    int* minpos = (int*)((char*)d_ws + (size_t)BDIM * DDIM * 2);
    int* maxneg = minpos + BDIM;

    cvt_init_kernel<<<dim3((BDIM * DDIM / 4) / 256), dim3(256), 0, stream>>>(emb, Ebf, minpos, maxneg);
    triplet_main<<<dim3(528), dim3(256), 0, stream>>>(Ebf, labels, minpos, maxneg);
    finalize_kernel<<<dim3(1), dim3(1024), 0, stream>>>(minpos, maxneg, out);
}